// Round 6
// baseline (1242.747 us; speedup 1.0000x reference)
//
#include <hip/hip_runtime.h>

#define NT 16384   // tokens
#define DM 4096    // d_model
#define NE 64      // experts
#define TPB 8      // tokens per block
#define NCH 16     // k-chunks of 256 (lane l owns k = 4l + 256c)

typedef __attribute__((address_space(3))) float lds_f;
typedef __attribute__((address_space(1))) const float glb_f;

__device__ __forceinline__ int bitrev6(int l) {
  return ((l & 1) << 5) | ((l & 2) << 3) | ((l & 4) << 1) |
         ((l & 8) >> 1) | ((l & 16) >> 3) | ((l & 32) >> 5);
}

// 6-level butterfly: after this, lane l holds the 64-lane total of a[bitrev6(l)]
// in a[0]. (R4-validated, absmax 0.)
__device__ __forceinline__ void butterfly64(float* a, int lane) {
#pragma unroll
  for (int s = 0; s < 6; ++s) {
    const int n = 32 >> s;
    const bool hi = (lane >> s) & 1;
#pragma unroll
    for (int i = 0; i < n; ++i) {
      const float mine  = hi ? a[i] : a[i + n];
      const float keep  = hi ? a[i + n] : a[i];
      const float other = __shfl_xor(mine, 1 << s, 64);
      a[i] = keep + other;
    }
  }
}

#define COMPUTE(XS, WF)                                            \
  {                                                                \
    _Pragma("unroll")                                              \
    for (int t = 0; t < TPB; ++t) {                                \
      const float4 xv = *(const float4*)(&XS[t][lane * 4]);        \
      _Pragma("unroll")                                            \
      for (int j = 0; j < 8; ++j) {                                \
        float a = acc[t * 8 + j];                                  \
        a = fmaf(xv.x, WF[j].x, a);                                \
        a = fmaf(xv.y, WF[j].y, a);                                \
        a = fmaf(xv.z, WF[j].z, a);                                \
        a = fmaf(xv.w, WF[j].w, a);                                \
        acc[t * 8 + j] = a;                                        \
      }                                                            \
    }                                                              \
  }

// Kernel 1: logits GEMM. Block = 256 threads = 4 waves = 8 tok x 32 exp
// (thread = 8 tok x 8 exp, lane owns k = 4l + 256c — R4's proven register
// structure, acc[64], no spill). x staged global_load_lds -> linear LDS
// (conflict-free b128 reads); W per-lane coalesced float4, double-buffered.
// bid bit3 = expert half, so the two blocks sharing an x tile map to the
// same XCD (bid%8). Accuracy: f32 64-seq per lane + f32 butterfly tree
// (validated, absmax 0).
__launch_bounds__(256, 3)
__global__ void moe_logits(const float* __restrict__ x,
                           const float* __restrict__ W,
                           float* __restrict__ logits) {
  __shared__ float xs0[TPB][256];   // 8 KiB
  __shared__ float xs1[TPB][256];   // 8 KiB

  const int tid  = threadIdx.x;
  const int lane = tid & 63;
  const int wvu  = __builtin_amdgcn_readfirstlane(tid >> 6);  // 0..3
  const int bid  = blockIdx.x;

  const int h       = (bid >> 3) & 1;
  const int tokTile = (bid & 7) | ((bid >> 4) << 3);
  const int tok0    = tokTile * TPB;

  // staging: wave w stages token rows 2w, 2w+1 (one glds each, 16B/lane)
  const float* xg0 = x + (size_t)(tok0 + 2 * wvu) * DM + lane * 4;
  const float* xg1 = xg0 + DM;
  float* l0 = &xs0[2 * wvu][0];
  float* l1 = &xs0[2 * wvu + 1][0];
  float* m0 = &xs1[2 * wvu][0];
  float* m1 = &xs1[2 * wvu + 1][0];

  // W: per-lane coalesced; wave w -> experts h*32 + [8w, 8w+8)
  const float* wp = W + (size_t)(h * 32 + wvu * 8) * DM + lane * 4;

  float acc[64];
#pragma unroll
  for (int i = 0; i < 64; ++i) acc[i] = 0.f;

  float4 wA[8], wB[8];

  // prologue: stage chunk 0 -> xs0, load wA(0)
  __builtin_amdgcn_global_load_lds((const glb_f*)xg0, (lds_f*)l0, 16, 0, 0);
  __builtin_amdgcn_global_load_lds((const glb_f*)xg1, (lds_f*)l1, 16, 0, 0);
#pragma unroll
  for (int j = 0; j < 8; ++j) wA[j] = *(const float4*)(wp + (size_t)j * DM);
  __syncthreads();

  for (int c = 0; c < NCH; c += 2) {
    // stage chunk c+1 -> xs1, prefetch wB(c+1)   (c+1 <= 15: always valid)
    __builtin_amdgcn_global_load_lds((const glb_f*)(xg0 + (c + 1) * 256), (lds_f*)m0, 16, 0, 0);
    __builtin_amdgcn_global_load_lds((const glb_f*)(xg1 + (c + 1) * 256), (lds_f*)m1, 16, 0, 0);
#pragma unroll
    for (int j = 0; j < 8; ++j) wB[j] = *(const float4*)(wp + (size_t)j * DM + (c + 1) * 256);

    COMPUTE(xs0, wA)
    __syncthreads();   // xs1 staged; all waves done with xs0

    if (c + 2 < NCH) {
      __builtin_amdgcn_global_load_lds((const glb_f*)(xg0 + (c + 2) * 256), (lds_f*)l0, 16, 0, 0);
      __builtin_amdgcn_global_load_lds((const glb_f*)(xg1 + (c + 2) * 256), (lds_f*)l1, 16, 0, 0);
#pragma unroll
      for (int j = 0; j < 8; ++j) wA[j] = *(const float4*)(wp + (size_t)j * DM + (c + 2) * 256);
    }

    COMPUTE(xs1, wB)
    __syncthreads();
  }

  // cross-lane reduce; lane l ends with total for acc[bitrev6(l)]
  butterfly64(acc, lane);
  const int a = bitrev6(lane);
  const int t = a >> 3;
  const int j = a & 7;
  logits[(size_t)(tok0 + t) * NE + h * 32 + wvu * 8 + j] = acc[0];
}

// Kernel 2: softmax + top-2 + per-block expert sums (R4-validated verbatim).
// Grid 256 x 512 threads; wave wv owns 8 tokens.
__launch_bounds__(512, 2)
__global__ void moe_topk(const float* __restrict__ logits,
                         float* __restrict__ out,
                         float* __restrict__ bsum) {
  __shared__ float esums[8][64];
  const int tid  = threadIdx.x;
  const int lane = tid & 63;
  const int wv   = tid >> 6;
  const int blk  = blockIdx.x;

  float esum = 0.f;
  for (int ti = 0; ti < 8; ++ti) {
    const int t = blk * 64 + wv * 8 + ti;
    const float lg = logits[(size_t)t * NE + lane];

    float m = lg;
#pragma unroll
    for (int off = 32; off; off >>= 1) m = fmaxf(m, __shfl_xor(m, off, 64));
    const float p = __expf(lg - m);
    float Z = p;
#pragma unroll
    for (int off = 32; off; off >>= 1) Z += __shfl_xor(Z, off, 64);
    const float s = p / Z;
    esum += s;

    // top-1 (value desc, index asc — matches lax.top_k tie-break)
    float v1 = s; int i1 = lane;
#pragma unroll
    for (int off = 32; off; off >>= 1) {
      const float ov = __shfl_xor(v1, off, 64);
      const int   oi = __shfl_xor(i1, off, 64);
      if (ov > v1 || (ov == v1 && oi < i1)) { v1 = ov; i1 = oi; }
    }
    // top-2: mask winner (scores >= 0, so -1 acts as -inf)
    float sv = (lane == i1) ? -1.f : s;
    float v2 = sv; int i2 = lane;
#pragma unroll
    for (int off = 32; off; off >>= 1) {
      const float ov = __shfl_xor(v2, off, 64);
      const int   oi = __shfl_xor(i2, off, 64);
      if (ov > v2 || (ov == v2 && oi < i2)) { v2 = ov; i2 = oi; }
    }

    if (lane == 0) {
      const float inv = 1.f / (v1 + v2);
      out[2 * t]              = v1 * inv;
      out[2 * t + 1]          = v2 * inv;
      out[2 * NT + 2 * t]     = (float)i1;
      out[2 * NT + 2 * t + 1] = (float)i2;
    }
  }

  esums[wv][lane] = esum;
  __syncthreads();
  if (wv == 0) {
    float tot = 0.f;
#pragma unroll
    for (int w = 0; w < 8; ++w) tot += esums[w][lane];
    bsum[blk * NE + lane] = tot;
  }
}

// Kernel 3: reduce 256 per-block expert sums -> load balancing loss
__global__ void moe_gate_loss(const float* __restrict__ bsum,
                              float* __restrict__ out) {
  __shared__ float red[4][64];
  const int e = threadIdx.x & 63;
  const int g = threadIdx.x >> 6;
  float s = 0.f;
  for (int b = g; b < 256; b += 4) s += bsum[b * 64 + e];
  red[g][e] = s;
  __syncthreads();
  if (threadIdx.x < 64) {
    const float tot = red[0][e] + red[1][e] + red[2][e] + red[3][e];
    const float p = tot * (1.f / (float)NT);
    float term = p * logf(p + 1e-8f);
#pragma unroll
    for (int off = 32; off; off >>= 1) term += __shfl_xor(term, off, 64);
    if (e == 0) out[4 * NT] = term;  // out[65536]
  }
}

extern "C" void kernel_launch(void* const* d_in, const int* in_sizes, int n_in,
                              void* d_out, int out_size, void* d_ws, size_t ws_size,
                              hipStream_t stream) {
  const float* x = (const float*)d_in[0];   // [16384, 4096]
  const float* W = (const float*)d_in[1];   // [64, 4096]
  float* out = (float*)d_out;               // scores[32768] | idx[32768] | loss[1]
  float* logits = (float*)d_ws;             // [16384][64] f32 = 4 MiB
  float* bsum = logits + (size_t)NT * NE;   // [256][64]

  hipLaunchKernelGGL(moe_logits, dim3((NT / TPB) * 2), dim3(256), 0, stream, x, W, logits);
  hipLaunchKernelGGL(moe_topk, dim3(NT / 64), dim3(512), 0, stream, logits, out, bsum);
  hipLaunchKernelGGL(moe_gate_loss, dim3(1), dim3(256), 0, stream, bsum, out);
}

// Round 7
// 97.545 us; speedup vs baseline: 12.7402x; 12.7402x over previous
//
#include <hip/hip_runtime.h>

#define NT 16384   // tokens
#define DM 4096    // d_model
#define NE 64      // experts
#define MB 64      // tokens per block
#define KSPLIT 8   // K split across the 8 waves
#define KW (DM / KSPLIT)   // 512 k per wave
#define KSTEPS (KW / 32)   // 16 mfma K-steps per wave

typedef __attribute__((ext_vector_type(8))) short bf16x8;   // 8 bf16 = 4 VGPRs
typedef __attribute__((ext_vector_type(4))) float f32x4;

__device__ __forceinline__ unsigned short bf16_rne(float f) {
  const unsigned u = __float_as_uint(f);
  return (unsigned short)((u + 0x7FFFu + ((u >> 16) & 1u)) >> 16);
}

// W pre-pass: fp32 -> split bf16 hi/lo, stored in exact MFMA B-fragment order.
// id = ks*256 + nt*64 + lane; elem j = W[e=nt*16+(lane&15)][k=ks*32+(lane>>4)*8+j].
// Idempotent (graph-replay safe), runs every launch.
__global__ void w_convert(const float* __restrict__ W,
                          unsigned short* __restrict__ Whi,
                          unsigned short* __restrict__ Wlo) {
  const int id   = blockIdx.x * 256 + threadIdx.x;  // 0..32767
  const int lane = id & 63;
  const int nt   = (id >> 6) & 3;
  const int ks   = id >> 8;                         // 0..127
  const float* src = W + (size_t)(nt * 16 + (lane & 15)) * DM + ks * 32 + (lane >> 4) * 8;
  unsigned short h[8], l[8];
#pragma unroll
  for (int j = 0; j < 8; ++j) {
    const float f = src[j];
    h[j] = bf16_rne(f);
    l[j] = bf16_rne(f - __uint_as_float((unsigned)h[j] << 16));
  }
  uint4 ph, pl;
  ph.x = h[0] | ((unsigned)h[1] << 16); ph.y = h[2] | ((unsigned)h[3] << 16);
  ph.z = h[4] | ((unsigned)h[5] << 16); ph.w = h[6] | ((unsigned)h[7] << 16);
  pl.x = l[0] | ((unsigned)l[1] << 16); pl.y = l[2] | ((unsigned)l[3] << 16);
  pl.z = l[4] | ((unsigned)l[5] << 16); pl.w = l[6] | ((unsigned)l[7] << 16);
  *(uint4*)(Whi + (size_t)id * 8) = ph;
  *(uint4*)(Wlo + (size_t)id * 8) = pl;
}

// Main: block = 512 thr = 8 waves; wave w = all 64 block-tokens x all 64 experts
// x K-slice [w*512,(w+1)*512). A-frags loaded per-lane straight from x (fp32) and
// split to bf16 hi/lo in registers — frag layout row=l&15, k=(l>>4)*8+j equals a
// 2xfloat4 load. 4-pass mfma (hh+hl+lh+ll) == fp32-accurate dot product.
// No LDS/barriers in the K loop; deterministic slab combine; validated epilogue.
__launch_bounds__(512, 2)
__global__ void moe_mfma(const float* __restrict__ x,
                         const unsigned short* __restrict__ Whi,
                         const unsigned short* __restrict__ Wlo,
                         float* __restrict__ out,
                         float* __restrict__ bsum) {
  __shared__ float slab[8][8][66];   // [ksplit-wave][tok-in-slice][expert] 16.9 KiB
  __shared__ float esums[8][NE];

  const int tid  = threadIdx.x;
  const int lane = tid & 63;
  const int wv   = tid >> 6;
  const int wvu  = __builtin_amdgcn_readfirstlane(wv);
  const int blk  = blockIdx.x;

  const float* ap[4];
#pragma unroll
  for (int mt = 0; mt < 4; ++mt)
    ap[mt] = x + (size_t)(blk * MB + mt * 16 + (lane & 15)) * DM + wv * KW + (lane >> 4) * 8;

  const int ks0 = wv * KSTEPS;   // this wave's global kstep base

  f32x4 acc[4][4];
#pragma unroll
  for (int mt = 0; mt < 4; ++mt)
#pragma unroll
    for (int nt = 0; nt < 4; ++nt) acc[mt][nt] = (f32x4){0.f, 0.f, 0.f, 0.f};

  float4 c0[4], c1[4];
#pragma unroll
  for (int mt = 0; mt < 4; ++mt) {
    c0[mt] = *(const float4*)(ap[mt]);
    c1[mt] = *(const float4*)(ap[mt] + 4);
  }

#pragma unroll 2
  for (int i = 0; i < KSTEPS; ++i) {
    float4 n0[4], n1[4];
    if (i + 1 < KSTEPS) {    // prefetch next kstep's x (HBM latency hides under mfma)
#pragma unroll
      for (int mt = 0; mt < 4; ++mt) {
        n0[mt] = *(const float4*)(ap[mt] + (i + 1) * 32);
        n1[mt] = *(const float4*)(ap[mt] + (i + 1) * 32 + 4);
      }
    }
    // B fragments (precomputed order, L2/L3-hot, coalesced 16B/lane)
    const size_t fb = (size_t)(ks0 + i) * 4 * 512;
    bf16x8 bh[4], bl[4];
#pragma unroll
    for (int nt = 0; nt < 4; ++nt) {
      bh[nt] = *(const bf16x8*)(Whi + fb + nt * 512 + lane * 8);
      bl[nt] = *(const bf16x8*)(Wlo + fb + nt * 512 + lane * 8);
    }
    // split-convert A in registers
    bf16x8 ah[4], al[4];
#pragma unroll
    for (int mt = 0; mt < 4; ++mt) {
      float fr[8];
      fr[0] = c0[mt].x; fr[1] = c0[mt].y; fr[2] = c0[mt].z; fr[3] = c0[mt].w;
      fr[4] = c1[mt].x; fr[5] = c1[mt].y; fr[6] = c1[mt].z; fr[7] = c1[mt].w;
#pragma unroll
      for (int j = 0; j < 8; ++j) {
        const unsigned short hb = bf16_rne(fr[j]);
        ah[mt][j] = (short)hb;
        al[mt][j] = (short)bf16_rne(fr[j] - __uint_as_float((unsigned)hb << 16));
      }
    }
    // 4-pass mfma: ll + lh + hl + hh (bf16 products exact in fp32)
#pragma unroll
    for (int mt = 0; mt < 4; ++mt)
#pragma unroll
      for (int nt = 0; nt < 4; ++nt) {
        acc[mt][nt] = __builtin_amdgcn_mfma_f32_16x16x32_bf16(al[mt], bl[nt], acc[mt][nt], 0, 0, 0);
        acc[mt][nt] = __builtin_amdgcn_mfma_f32_16x16x32_bf16(al[mt], bh[nt], acc[mt][nt], 0, 0, 0);
        acc[mt][nt] = __builtin_amdgcn_mfma_f32_16x16x32_bf16(ah[mt], bl[nt], acc[mt][nt], 0, 0, 0);
        acc[mt][nt] = __builtin_amdgcn_mfma_f32_16x16x32_bf16(ah[mt], bh[nt], acc[mt][nt], 0, 0, 0);
      }
    if (i + 1 < KSTEPS) {
#pragma unroll
      for (int mt = 0; mt < 4; ++mt) { c0[mt] = n0[mt]; c1[mt] = n1[mt]; }
    }
  }

  // Deterministic k-split combine. D layout (m89): row=(l>>4)*4+r, col=l&15.
  // Round s: every wave writes its partial for token-slice s; wave s sums 8 slabs.
  float lg[8];
#pragma unroll
  for (int s = 0; s < 8; ++s) {
    const int mt = s >> 1, g = 2 * (s & 1);
    const int q = lane >> 4;
    if (q == g || q == g + 1) {
#pragma unroll
      for (int nt = 0; nt < 4; ++nt)
#pragma unroll
        for (int r = 0; r < 4; ++r)
          slab[wv][(q - g) * 4 + r][nt * 16 + (lane & 15)] = acc[mt][nt][r];
    }
    __syncthreads();
    if (wvu == s) {
#pragma unroll
      for (int t = 0; t < 8; ++t) {
        float v = 0.f;
#pragma unroll
        for (int w = 0; w < 8; ++w) v += slab[w][t][lane];
        lg[t] = v;
      }
    }
    __syncthreads();
  }

  // Epilogue (validated): wave wvu owns tokens blk*64 + wvu*8 + ti; lane <-> expert.
  float esum = 0.f;
#pragma unroll
  for (int ti = 0; ti < 8; ++ti) {
    const float lgv = lg[ti];
    float m = lgv;
#pragma unroll
    for (int off = 32; off; off >>= 1) m = fmaxf(m, __shfl_xor(m, off, 64));
    const float p = __expf(lgv - m);
    float Z = p;
#pragma unroll
    for (int off = 32; off; off >>= 1) Z += __shfl_xor(Z, off, 64);
    const float s = p / Z;
    esum += s;

    // top-1 (value desc, index asc — matches lax.top_k tie-break)
    float v1 = s; int i1 = lane;
#pragma unroll
    for (int off = 32; off; off >>= 1) {
      const float ov = __shfl_xor(v1, off, 64);
      const int   oi = __shfl_xor(i1, off, 64);
      if (ov > v1 || (ov == v1 && oi < i1)) { v1 = ov; i1 = oi; }
    }
    // top-2: mask winner (scores >= 0, so -1 acts as -inf)
    float sv = (lane == i1) ? -1.f : s;
    float v2 = sv; int i2 = lane;
#pragma unroll
    for (int off = 32; off; off >>= 1) {
      const float ov = __shfl_xor(v2, off, 64);
      const int   oi = __shfl_xor(i2, off, 64);
      if (ov > v2 || (ov == v2 && oi < i2)) { v2 = ov; i2 = oi; }
    }

    if (lane == 0) {
      const int gt = blk * MB + wvu * 8 + ti;
      const float inv = 1.f / (v1 + v2);
      out[2 * gt]              = v1 * inv;
      out[2 * gt + 1]          = v2 * inv;
      out[2 * NT + 2 * gt]     = (float)i1;
      out[2 * NT + 2 * gt + 1] = (float)i2;
    }
  }

  // per-block expert score sums (deterministic tree reduce, no atomics)
  esums[wvu][lane] = esum;
  __syncthreads();
  if (wvu == 0) {
    float tot = 0.f;
#pragma unroll
    for (int w = 0; w < 8; ++w) tot += esums[w][lane];
    bsum[blk * NE + lane] = tot;
  }
}

// Reduce 256 per-block expert sums -> load balancing loss
__global__ void moe_gate_loss(const float* __restrict__ bsum,
                              float* __restrict__ out) {
  __shared__ float red[4][64];
  const int e = threadIdx.x & 63;
  const int g = threadIdx.x >> 6;
  float s = 0.f;
  for (int b = g; b < NT / MB; b += 4) s += bsum[b * 64 + e];
  red[g][e] = s;
  __syncthreads();
  if (threadIdx.x < 64) {
    const float tot = red[0][e] + red[1][e] + red[2][e] + red[3][e];
    const float p = tot * (1.f / (float)NT);
    float term = p * logf(p + 1e-8f);
#pragma unroll
    for (int off = 32; off; off >>= 1) term += __shfl_xor(term, off, 64);
    if (e == 0) out[4 * NT] = term;  // out[65536]
  }
}

extern "C" void kernel_launch(void* const* d_in, const int* in_sizes, int n_in,
                              void* d_out, int out_size, void* d_ws, size_t ws_size,
                              hipStream_t stream) {
  const float* x = (const float*)d_in[0];   // [16384, 4096]
  const float* W = (const float*)d_in[1];   // [64, 4096]
  float* out = (float*)d_out;               // scores[32768] | idx[32768] | loss[1]

  unsigned short* Whi = (unsigned short*)d_ws;        // 512 KiB
  unsigned short* Wlo = Whi + (size_t)NE * DM;        // 512 KiB
  float* bsum = (float*)(Wlo + (size_t)NE * DM);      // [256][64]

  hipLaunchKernelGGL(w_convert, dim3(128), dim3(256), 0, stream, W, Whi, Wlo);
  hipLaunchKernelGGL(moe_mfma, dim3(NT / MB), dim3(512), 0, stream, x, Whi, Wlo, out, bsum);
  hipLaunchKernelGGL(moe_gate_loss, dim3(1), dim3(256), 0, stream, bsum, out);
}